// Round 18
// baseline (177.496 us; speedup 1.0000x reference)
//
#include <hip/hip_runtime.h>

// Problem constants
#define BB 4
#define CC 16
#define HH 256
#define WW 256
#define NN (HH*WW)      // 65536
#define SS 100
#define EPSV 1e-32f

// ws layout (float offsets)
#define PQ_OFF    0u                      // [8 bq][100 s][17]           = 13600
#define SPFN_OFF  13600u                  // [8 bq][100 s][16 c]         = 12800
#define PFSP_OFF  26400u                  // [4][16][65536]              = 4194304
#define PPART_OFF PFSP_OFF                // [8][256 win][100 s][17]     = 3481600
// PPART aliases PFSP: consumed by k_reduceP before k_pass2 overwrites.

typedef __fp16 h2 __attribute__((ext_vector_type(2)));

__device__ __forceinline__ float sum4(const float4& a) {
    return a.x + a.y + a.z + a.w;
}
__device__ __forceinline__ h2 as_h2(float f) {
    union { float f; h2 h; } u; u.f = f; return u.h;
}

#if __has_builtin(__builtin_amdgcn_fdot2)
__device__ __forceinline__ float fdot2(h2 a, h2 b, float c) {
    return __builtin_amdgcn_fdot2(a, b, c, false);
}
#else
__device__ __forceinline__ float fdot2(h2 a, h2 b, float c) {
    return c + (float)a.x * (float)b.x + (float)a.y * (float)b.y;
}
#endif

// DPP lane-combine. Uniform control flow only (R9 lesson).
#define DPPQP(x, ctrl) __int_as_float(__builtin_amdgcn_update_dpp( \
    0, __float_as_int(x), ctrl, 0xF, 0xF, true))
// 0xB1 qp xor1; 0x4E qp xor2; 0x111/0x112/0x114/0x118 row_shr 1/2/4/8

// ---------------- pass1 (K1) ----------------
// R17 zero-amplification structure at 2x parallelism: 256-px windows,
// 2048 blocks (8/CU), 8KB LDS f16 pf staged once/block, each wave owns all
// 16 c x window x private 25-s slice. Per s: ONE float4 Q load, 16
// ds_read_b64, 32 fdot2, verified merge tree (xor1/xor2 + sel, row_shr4+8,
// shfl_xor16) + shfl_xor32 full merge -> lanes 12-15 store [17] per s.
#define P1_DOT(dst, c) { \
    float2 rc = *(const float2*)&pfl[c][lane][0]; \
    dst = fdot2(as_h2(rc.x), hq0, fdot2(as_h2(rc.y), hq1, 0.f)); \
}

#define P1_STEP(QA, sidx) { \
    float qv = sum4(QA); \
    h2 hq0 = __builtin_amdgcn_cvt_pkrtz(QA.x, QA.y); \
    h2 hq1 = __builtin_amdgcn_cvt_pkrtz(QA.z, QA.w); \
    float t0, t1, t2, t3, t4, t5, t6, t7, t8, t9, t10, t11, t12, t13, t14, t15; \
    P1_DOT(t0, 0)  P1_DOT(t1, 1)  P1_DOT(t2, 2)  P1_DOT(t3, 3) \
    P1_DOT(t4, 4)  P1_DOT(t5, 5)  P1_DOT(t6, 6)  P1_DOT(t7, 7) \
    P1_DOT(t8, 8)  P1_DOT(t9, 9)  P1_DOT(t10, 10) P1_DOT(t11, 11) \
    P1_DOT(t12, 12) P1_DOT(t13, 13) P1_DOT(t14, 14) P1_DOT(t15, 15) \
    t0 += DPPQP(t0,0xB1);   t1 += DPPQP(t1,0xB1); \
    t2 += DPPQP(t2,0xB1);   t3 += DPPQP(t3,0xB1); \
    t4 += DPPQP(t4,0xB1);   t5 += DPPQP(t5,0xB1); \
    t6 += DPPQP(t6,0xB1);   t7 += DPPQP(t7,0xB1); \
    t8 += DPPQP(t8,0xB1);   t9 += DPPQP(t9,0xB1); \
    t10 += DPPQP(t10,0xB1); t11 += DPPQP(t11,0xB1); \
    t12 += DPPQP(t12,0xB1); t13 += DPPQP(t13,0xB1); \
    t14 += DPPQP(t14,0xB1); t15 += DPPQP(t15,0xB1); \
    float v0 = odd ? t1 : t0;   float v1 = odd ? t3 : t2; \
    float v2 = odd ? t5 : t4;   float v3 = odd ? t7 : t6; \
    float v4 = odd ? t9 : t8;   float v5 = odd ? t11 : t10; \
    float v6 = odd ? t13 : t12; float v7 = odd ? t15 : t14; \
    v0 += DPPQP(v0,0x4E); v1 += DPPQP(v1,0x4E); \
    v2 += DPPQP(v2,0x4E); v3 += DPPQP(v3,0x4E); \
    v4 += DPPQP(v4,0x4E); v5 += DPPQP(v5,0x4E); \
    v6 += DPPQP(v6,0x4E); v7 += DPPQP(v7,0x4E); \
    float w0 = hi2 ? v1 : v0; float w1 = hi2 ? v3 : v2; \
    float w2 = hi2 ? v5 : v4; float w3 = hi2 ? v7 : v6; \
    w0 += DPPQP(w0,0x114); w1 += DPPQP(w1,0x114); \
    w2 += DPPQP(w2,0x114); w3 += DPPQP(w3,0x114); \
    w0 += DPPQP(w0,0x118); w1 += DPPQP(w1,0x118); \
    w2 += DPPQP(w2,0x118); w3 += DPPQP(w3,0x118); \
    w0 += __shfl_xor(w0,16); w1 += __shfl_xor(w1,16); \
    w2 += __shfl_xor(w2,16); w3 += __shfl_xor(w3,16); \
    w0 += __shfl_xor(w0,32); w1 += __shfl_xor(w1,32); \
    w2 += __shfl_xor(w2,32); w3 += __shfl_xor(w3,32); \
    qv += DPPQP(qv,0x111); qv += DPPQP(qv,0x112); \
    qv += DPPQP(qv,0x114); qv += DPPQP(qv,0x118); \
    qv += __shfl_xor(qv,16); qv += __shfl_xor(qv,32); \
    if (lane >= 12 && lane < 16) { \
        float* o = sout + (size_t)(sidx)*17 + (lane & 3); \
        o[0] = w0; o[4] = w1; o[8] = w2; o[12] = w3; \
    } \
    if (lane == 15) sout[(size_t)(sidx)*17 + 16] = qv; \
}

__global__ __launch_bounds__(256) void k_pass1(const float* __restrict__ pf,
                                               const float* __restrict__ Q1,
                                               const float* __restrict__ Q2,
                                               float* __restrict__ ws) {
    int tid = threadIdx.x, wid = tid >> 6, lane = tid & 63;
    int win = blockIdx.x;      // 0..255 (256-px window)
    int bq  = blockIdx.y;      // 0..7
    int b = bq >> 1, q = bq & 1;
    bool odd = lane & 1;
    bool hi2 = lane & 2;

    __shared__ __align__(16) __fp16 pfl[CC][64][4];   // 8 KB

    const float* PF = pf + (size_t)b * CC * NN + win * 256;
    // stage pf window -> LDS f16: 1024 float4 slots, 4 iters
    for (int i = 0; i < 4; ++i) {
        int slot = i * 256 + tid;
        int c = slot >> 6, pos = slot & 63;
        float4 v = *(const float4*)(PF + (size_t)c * NN + pos * 4);
        h2 a = __builtin_amdgcn_cvt_pkrtz(v.x, v.y);
        h2 b2 = __builtin_amdgcn_cvt_pkrtz(v.z, v.w);
        h2* dst = (h2*)&pfl[c][pos][0];
        dst[0] = a; dst[1] = b2;
    }
    __syncthreads();

    // wave w owns s in [w*25, w*25+25)
    const float* qptr = (q ? Q2 : Q1) + (size_t)b * SS * NN
                        + (size_t)(wid * 25) * NN + win * 256 + lane * 4;
    float* sout = ws + PPART_OFF
                + (size_t)((bq * 256 + win) * 100 + wid * 25) * 17;

    float4 Aa, Ba;
    Aa = *(const float4*)(qptr);
    #pragma unroll 2
    for (int i = 0; i < 12; ++i) {
        Ba = *(const float4*)(qptr + (size_t)(2 * i + 1) * NN);
        P1_STEP(Aa, 2 * i)
        Aa = *(const float4*)(qptr + (size_t)(2 * i + 2) * NN);
        P1_STEP(Ba, 2 * i + 1)
    }
    P1_STEP(Aa, 24)
}

// ---------------- K2: reduce over 256 windows (coalesced) ----------------
__global__ __launch_bounds__(256) void k_reduceP(float* __restrict__ ws) {
    int strip = blockIdx.x;  // 0..6
    int bq    = blockIdx.y;  // 0..7
    int idx = strip * 256 + threadIdx.x;
    if (idx < 1700) {
        const float* pp = ws + PPART_OFF + (size_t)bq * 256 * 1700 + idx;
        float a0 = 0.f, a1 = 0.f;
        #pragma unroll 4
        for (int win = 0; win < 256; win += 2) {
            a0 += pp[(size_t)win * 1700];
            a1 += pp[(size_t)(win + 1) * 1700];
        }
        ws[PQ_OFF + (size_t)bq * 1700 + idx] = a0 + a1;
    }
}

// ---------------- K3: rels + finalize (s-quarter split) ----------------
__global__ __launch_bounds__(256) void k_finalize(const float* __restrict__ spf1,
                                                  const float* __restrict__ spf2,
                                                  float* __restrict__ ws) {
    int sq = blockIdx.x;  // 0..3 (25 s each)
    int bq = blockIdx.y;  // 0..7
    int b = bq >> 1, q = bq & 1;
    __shared__ float sp[CC][SS];
    __shared__ float rl[25][SS + 1];
    __shared__ float Pl[CC * SS];
    __shared__ float qs[SS];
    __shared__ float den[25];
    int tid = threadIdx.x;

    const float* spf = (q ? spf2 : spf1) + (size_t)b * CC * SS;
    for (int i = tid; i < CC * SS; i += 256) sp[i / SS][i % SS] = spf[i];
    const float* pq = ws + PQ_OFF + (size_t)bq * 1700;
    for (int idx = tid; idx < CC * SS; idx += 256) {
        int c = idx / SS, t = idx % SS;
        Pl[idx] = pq[(size_t)t * 17 + c];
    }
    if (tid < SS) qs[tid] = pq[(size_t)tid * 17 + 16];
    __syncthreads();
    for (int i = tid; i < 25 * SS; i += 256) {
        int sl = i / SS, t = i % SS;
        int s = sq * 25 + sl;
        float d2 = 0.f;
        #pragma unroll
        for (int c = 0; c < CC; ++c) {
            float d = sp[c][t] - sp[c][s];
            d2 += d * d;
        }
        rl[sl][t] = expf(-d2);
    }
    __syncthreads();
    if (tid < 25) {
        float a = 0.f;
        for (int t = 0; t < SS; ++t) a += rl[tid][t] * qs[t];
        den[tid] = a + EPSV;
    }
    __syncthreads();
    float* sout = ws + SPFN_OFF + (size_t)bq * SS * CC;
    for (int idx = tid; idx < 25 * CC; idx += 256) {
        int sl = idx / CC, c = idx % CC;
        float a = 0.f;
        for (int t = 0; t < SS; ++t) a += rl[sl][t] * Pl[c * SS + t];
        sout[(size_t)(sq * 25 + sl) * CC + c] = a / den[sl];
    }
}

// ---------------- K4: pf_sp = spf1n@Q1 + spf2n@Q2 ----------------
#define P2STEP(V1, V2, s) { \
    _Pragma("unroll") for (int g = 0; g < 4; ++g) { \
        float4 s1 = *(const float4*)&spl[(0 * SS + (s)) * CC + g * 4]; \
        float4 s2 = *(const float4*)&spl[(SS + (s)) * CC + g * 4]; \
        acc[g*4+0].x += s1.x*V1.x + s2.x*V2.x; \
        acc[g*4+0].y += s1.x*V1.y + s2.x*V2.y; \
        acc[g*4+1].x += s1.y*V1.x + s2.y*V2.x; \
        acc[g*4+1].y += s1.y*V1.y + s2.y*V2.y; \
        acc[g*4+2].x += s1.z*V1.x + s2.z*V2.x; \
        acc[g*4+2].y += s1.z*V1.y + s2.z*V2.y; \
        acc[g*4+3].x += s1.w*V1.x + s2.w*V2.x; \
        acc[g*4+3].y += s1.w*V1.y + s2.w*V2.y; } }

__global__ __launch_bounds__(128) void k_pass2(const float* __restrict__ Q1,
                                               const float* __restrict__ Q2,
                                               float* __restrict__ ws) {
    int blk = blockIdx.x;   // 0..255
    int b   = blockIdx.y;
    __shared__ float spl[2 * SS * CC];
    int tid = threadIdx.x;
    const float* spin = ws + SPFN_OFF + (size_t)b * 2 * SS * CC;
    for (int idx = tid; idx < 2 * SS * CC; idx += 128) spl[idx] = spin[idx];
    __syncthreads();
    int n = blk * 256 + tid * 2;
    const float* q1p = Q1 + (size_t)b * SS * NN + n;
    const float* q2p = Q2 + (size_t)b * SS * NN + n;
    float2 acc[CC];
    #pragma unroll
    for (int c = 0; c < CC; ++c) acc[c] = make_float2(0.f, 0.f);
    float2 A1, A2, B1, B2;
    A1 = *(const float2*)(q1p);
    A2 = *(const float2*)(q2p);
    #pragma unroll 2
    for (int s = 0; s < 98; s += 2) {
        B1 = *(const float2*)(q1p + (size_t)(s + 1) * NN);
        B2 = *(const float2*)(q2p + (size_t)(s + 1) * NN);
        P2STEP(A1, A2, s)
        A1 = *(const float2*)(q1p + (size_t)(s + 2) * NN);
        A2 = *(const float2*)(q2p + (size_t)(s + 2) * NN);
        P2STEP(B1, B2, s + 1)
    }
    B1 = *(const float2*)(q1p + (size_t)99 * NN);
    B2 = *(const float2*)(q2p + (size_t)99 * NN);
    P2STEP(A1, A2, 98)
    P2STEP(B1, B2, 99)
    float* o = ws + PFSP_OFF + (size_t)b * CC * NN + n;
    #pragma unroll
    for (int c = 0; c < CC; ++c)
        *(float2*)(o + (size_t)c * NN) = acc[c];
}

// ---------------- K5: 3x3 conv, 16 -> 2 channels, + bias ----------------
__global__ __launch_bounds__(256) void k_conv(const float* __restrict__ w_ds,
                                              const float* __restrict__ b_ds,
                                              const float* __restrict__ ws,
                                              float* __restrict__ out) {
    int b = blockIdx.y;
    int n = blockIdx.x * 256 + threadIdx.x;
    __shared__ float wl[2][CC][9];
    __shared__ float bl[2];
    for (int i = threadIdx.x; i < 2 * CC * 9; i += 256)
        ((float*)wl)[i] = w_ds[i];
    if (threadIdx.x < 2) bl[threadIdx.x] = b_ds[threadIdx.x];
    __syncthreads();
    int y = n >> 8, x = n & 255;
    const float* base = ws + PFSP_OFF + (size_t)b * CC * NN;
    float a0 = bl[0], a1 = bl[1];
    for (int c = 0; c < CC; ++c) {
        const float* pc = base + (size_t)c * NN;
        #pragma unroll
        for (int dy = -1; dy <= 1; ++dy) {
            int yy = y + dy;
            if (yy < 0 || yy >= HH) continue;
            #pragma unroll
            for (int dx = -1; dx <= 1; ++dx) {
                int xx = x + dx;
                if (xx < 0 || xx >= WW) continue;
                float v = pc[(size_t)yy * WW + xx];
                int k = (dy + 1) * 3 + (dx + 1);
                a0 += v * wl[0][c][k];
                a1 += v * wl[1][c][k];
            }
        }
    }
    out[((size_t)b * 2 + 0) * NN + n] = a0;
    out[((size_t)b * 2 + 1) * NN + n] = a1;
}

extern "C" void kernel_launch(void* const* d_in, const int* in_sizes, int n_in,
                              void* d_out, int out_size, void* d_ws, size_t ws_size,
                              hipStream_t stream) {
    const float* pf   = (const float*)d_in[0];
    const float* spf1 = (const float*)d_in[1];
    const float* spf2 = (const float*)d_in[2];
    const float* Q1   = (const float*)d_in[3];
    const float* Q2   = (const float*)d_in[4];
    const float* w_ds = (const float*)d_in[5];
    const float* b_ds = (const float*)d_in[6];
    float* ws  = (float*)d_ws;
    float* out = (float*)d_out;

    k_pass1<<<dim3(256, 8), 256, 0, stream>>>(pf, Q1, Q2, ws);
    k_reduceP<<<dim3(7, 8), 256, 0, stream>>>(ws);
    k_finalize<<<dim3(4, 8), 256, 0, stream>>>(spf1, spf2, ws);
    k_pass2<<<dim3(256, BB), 128, 0, stream>>>(Q1, Q2, ws);
    k_conv<<<dim3(NN / 256, BB), 256, 0, stream>>>(w_ds, b_ds, ws, out);
}